// Round 6
// baseline (504.258 us; speedup 1.0000x reference)
//
#include <hip/hip_runtime.h>

#define L 2048
#define D 1024
#define NH 16
#define HD 64
#define SPLIT 4
#define JCH (L / SPLIT)
#define LOG2E 1.4426950408889634f

typedef __attribute__((ext_vector_type(8))) short bf16x8;
typedef __attribute__((ext_vector_type(4))) float f32x4;

#define MFMA(a, b, c) __builtin_amdgcn_mfma_f32_16x16x32_bf16(a, b, c, 0, 0, 0)

__device__ __forceinline__ short f2bf(float x) {
  unsigned u = __float_as_uint(x);
  u = (u + 0x7FFFu + ((u >> 16) & 1u)) >> 16;  // RNE
  return (short)u;
}

// async global->LDS, 16B per lane. LDS dest = wave-uniform base + lane*16.
__device__ __forceinline__ void gll16(const void* g, void* l) {
  __builtin_amdgcn_global_load_lds(
      (const __attribute__((address_space(1))) void*)(uintptr_t)g,
      (__attribute__((address_space(3))) void*)(unsigned)(uintptr_t)l, 16, 0, 0);
}

// ---------------------------------------------------------------- trig table
__global__ void trig_kernel(float* __restrict__ costab, float* __restrict__ sintab) {
  int idx = blockIdx.x * blockDim.x + threadIdx.x;  // 65536 total
  int t = idx >> 5, fi = idx & 31;
  float f = exp2f(-(float)fi * (13.287712379549449f / 32.0f));  // 10000^(-fi/32)
  float ang = (float)t * f;
  costab[idx] = cosf(ang);
  sintab[idx] = sinf(ang);
}

// ---------------------------------------------------------------- f32 -> bf16
__global__ void f2bf4_kernel(const float* __restrict__ in, short* __restrict__ out, int n4) {
  int i = blockIdx.x * blockDim.x + threadIdx.x;
  if (i < n4) {
    float4 v = ((const float4*)in)[i];
    short4 o;
    o.x = f2bf(v.x); o.y = f2bf(v.y); o.z = f2bf(v.z); o.w = f2bf(v.w);
    ((short4*)out)[i] = o;
  }
}

// ---------------------------------------------------------------- projection
__global__ __launch_bounds__(256) void proj_kernel(
    const short* __restrict__ X, const short* __restrict__ W,
    const float* __restrict__ bias, const float* __restrict__ costab,
    const float* __restrict__ sintab, int mode,
    short* __restrict__ out_main, short* __restrict__ out_rope) {
  int w = threadIdx.x >> 6, lane = threadIdx.x & 63;
  int c = lane & 15, g = lane >> 4;
  int wi0 = blockIdx.y * 128 + (w >> 1) * 64;
  int wj0 = blockIdx.x * 128 + (w & 1) * 64;

  f32x4 acc[4][4];
#pragma unroll
  for (int m = 0; m < 4; ++m)
#pragma unroll
    for (int n = 0; n < 4; ++n) acc[m][n] = (f32x4){0.f, 0.f, 0.f, 0.f};

  for (int k0 = 0; k0 < D; k0 += 32) {
    bf16x8 aF[4], bF[4];
#pragma unroll
    for (int m = 0; m < 4; ++m)
      aF[m] = *(const bf16x8*)(X + (size_t)(wi0 + m * 16 + c) * D + k0 + g * 8);
#pragma unroll
    for (int n = 0; n < 4; ++n)
      bF[n] = *(const bf16x8*)(W + (size_t)(wj0 + n * 16 + c) * D + k0 + g * 8);
#pragma unroll
    for (int m = 0; m < 4; ++m)
#pragma unroll
      for (int n = 0; n < 4; ++n) acc[m][n] = MFMA(aF[m], bF[n], acc[m][n]);
  }

  float scale = (mode == 0) ? 0.125f : 1.0f;
#pragma unroll
  for (int m = 0; m < 4; ++m) {
#pragma unroll
    for (int r = 0; r < 4; ++r) {
      int i = wi0 + m * 16 + g * 4 + r;
      float v4[4];
#pragma unroll
      for (int n = 0; n < 4; ++n)
        v4[n] = (acc[m][n][r] + bias[wj0 + n * 16 + c]) * scale;
      if (mode == 2) {
#pragma unroll
        for (int n = 0; n < 4; ++n) {
          int col = wj0 + n * 16 + c;
          out_main[(size_t)col * L + i] = f2bf(v4[n]);  // Vt[col][i]
        }
      } else {
#pragma unroll
        for (int n = 0; n < 4; ++n) {
          int col = wj0 + n * 16 + c;
          out_main[(size_t)i * D + col] = f2bf(v4[n]);
          float rot = (n < 2) ? -v4[n + 2] : v4[n - 2];
          int fidx = i * 32 + (n & 1) * 16 + c;
          float vr = v4[n] * costab[fidx] + rot * sintab[fidx];
          out_rope[(size_t)i * D + col] = f2bf(vr);
        }
      }
    }
  }
}

// ---------------------------------------------------------------- avg dual-GEMM
// avg4[((i>>2)*L + j)] = f32x4 over i&3 of (QR@KR^T - Qs@Kb^T)/16
__global__ __launch_bounds__(256) void avg_kernel(
    const short* __restrict__ QR, const short* __restrict__ KR,
    const short* __restrict__ Qs, const short* __restrict__ Kb,
    f32x4* __restrict__ avg4) {
  int w = threadIdx.x >> 6, lane = threadIdx.x & 63;
  int c = lane & 15, g = lane >> 4;
  int wi0 = blockIdx.y * 128 + (w >> 1) * 64;
  int wj0 = blockIdx.x * 128 + (w & 1) * 64;

  f32x4 acc1[4][4], acc2[4][4];
#pragma unroll
  for (int m = 0; m < 4; ++m)
#pragma unroll
    for (int n = 0; n < 4; ++n) {
      acc1[m][n] = (f32x4){0.f, 0.f, 0.f, 0.f};
      acc2[m][n] = (f32x4){0.f, 0.f, 0.f, 0.f};
    }

  for (int k0 = 0; k0 < D; k0 += 32) {
    bf16x8 aF[4], bF[4], a2F[4], b2F[4];
#pragma unroll
    for (int m = 0; m < 4; ++m) {
      aF[m] = *(const bf16x8*)(QR + (size_t)(wi0 + m * 16 + c) * D + k0 + g * 8);
      a2F[m] = *(const bf16x8*)(Qs + (size_t)(wi0 + m * 16 + c) * D + k0 + g * 8);
    }
#pragma unroll
    for (int n = 0; n < 4; ++n) {
      bF[n] = *(const bf16x8*)(KR + (size_t)(wj0 + n * 16 + c) * D + k0 + g * 8);
      b2F[n] = *(const bf16x8*)(Kb + (size_t)(wj0 + n * 16 + c) * D + k0 + g * 8);
    }
#pragma unroll
    for (int m = 0; m < 4; ++m)
#pragma unroll
      for (int n = 0; n < 4; ++n) {
        acc1[m][n] = MFMA(aF[m], bF[n], acc1[m][n]);
        acc2[m][n] = MFMA(a2F[m], b2F[n], acc2[m][n]);
      }
  }

#pragma unroll
  for (int m = 0; m < 4; ++m)
#pragma unroll
    for (int n = 0; n < 4; ++n) {
      int j = wj0 + n * 16 + c;
      f32x4 o;
#pragma unroll
      for (int r = 0; r < 4; ++r) o[r] = (acc1[m][n][r] - acc2[m][n][r]) * 0.0625f;
      avg4[(size_t)(((wi0 + m * 16) >> 2) + g) * L + j] = o;
    }
}

// ---------------------------------------------------------------- single-pass flash, KV-split
// grid (L/64, NH, SPLIT). 4 waves, 16 rows each. K/KR tiles staged in LDS via
// global_load_lds (async, double-buffered, XOR-swizzled); V direct from global.
__global__ __launch_bounds__(256) void flash3_kernel(
    const short* __restrict__ Qs, const short* __restrict__ Kb,
    const short* __restrict__ QR, const short* __restrict__ KR,
    const short* __restrict__ Vt, const f32x4* __restrict__ avg4,
    const int* __restrict__ ids, float* __restrict__ m_part,
    float* __restrict__ l_part, float* __restrict__ acc_part) {
  int h = blockIdx.y, sp = blockIdx.z;
  int w = threadIdx.x >> 6, lane = threadIdx.x & 63;
  int c = lane & 15, g = lane >> 4;
  int i0 = blockIdx.x * 64 + w * 16;
  int hk = h * 64;

  // [2 buf][64 rows][64 shorts]; 16B chunk at (row, ch) holds global chunk ch^(row&7)
  __shared__ short kb_lds[2][64 * 64];
  __shared__ short kr_lds[2][64 * 64];
  __shared__ short plds[4][16][72];

  // staging: wave w covers rows w*16..w*16+15 per subtile; lane l -> dest row
  // r0+ (l>>3), dest chunk l&7, source chunk (l&7)^(l>>3)  (r0 % 8 == 0)
  int srow = lane >> 3;
  int sxor = (lane & 7) ^ srow;
  int r0a = w * 16, r0b = w * 16 + 8;

  bf16x8 qA[2], qrA[2];
  {
    const short* qp = Qs + (size_t)(i0 + c) * D + hk + g * 8;
    const short* qrp = QR + (size_t)(i0 + c) * D + hk + g * 8;
    qA[0] = *(const bf16x8*)qp;   qA[1] = *(const bf16x8*)(qp + 32);
    qrA[0] = *(const bf16x8*)qrp; qrA[1] = *(const bf16x8*)(qrp + 32);
  }

  int idi[4];
  float mrun[4], lsum[4];
  f32x4 acc[4];
#pragma unroll
  for (int r = 0; r < 4; ++r) {
    idi[r] = ids[i0 + g * 4 + r];
    mrun[r] = -3.0e38f;
    lsum[r] = 0.f;
  }
#pragma unroll
  for (int n = 0; n < 4; ++n) acc[n] = (f32x4){0.f, 0.f, 0.f, 0.f};

  const f32x4* avrow = avg4 + (size_t)((i0 >> 2) + g) * L;
  int jbase = sp * JCH;
  const int NT = JCH / 64;

  // prologue: stage tile 0 + prefetch tile 0 avg/ids
  gll16(Kb + (size_t)(jbase + r0a + srow) * D + hk + sxor * 8, &kb_lds[0][r0a * 64]);
  gll16(Kb + (size_t)(jbase + r0b + srow) * D + hk + sxor * 8, &kb_lds[0][r0b * 64]);
  gll16(KR + (size_t)(jbase + r0a + srow) * D + hk + sxor * 8, &kr_lds[0][r0a * 64]);
  gll16(KR + (size_t)(jbase + r0b + srow) * D + hk + sxor * 8, &kr_lds[0][r0b * 64]);

  f32x4 avn[4];
  int idjn[4];
#pragma unroll
  for (int sub = 0; sub < 4; ++sub) {
    avn[sub] = avrow[jbase + sub * 16 + c];
    idjn[sub] = ids[jbase + sub * 16 + c];
  }
  __syncthreads();  // drains vmcnt -> tile 0 staged

  int cur = 0;
  for (int jt = 0; jt < NT; ++jt) {
    int jb = jbase + jt * 64;

    // issue next tile's staging (in flight during this tile's compute)
    if (jt + 1 < NT) {
      int jn = jb + 64;
      short* kd = &kb_lds[cur ^ 1][0];
      short* rd = &kr_lds[cur ^ 1][0];
      gll16(Kb + (size_t)(jn + r0a + srow) * D + hk + sxor * 8, kd + r0a * 64);
      gll16(Kb + (size_t)(jn + r0b + srow) * D + hk + sxor * 8, kd + r0b * 64);
      gll16(KR + (size_t)(jn + r0a + srow) * D + hk + sxor * 8, rd + r0a * 64);
      gll16(KR + (size_t)(jn + r0b + srow) * D + hk + sxor * 8, rd + r0b * 64);
    }

    // V loads early (consumed at PV, covered by QK+softmax)
    bf16x8 vf0[4], vf1[4];
#pragma unroll
    for (int n = 0; n < 4; ++n) {
      const short* vp = Vt + (size_t)(hk + n * 16 + c) * L + jb + g * 8;
      vf0[n] = *(const bf16x8*)vp;
      vf1[n] = *(const bf16x8*)(vp + 32);
    }

    // rotate avg/ids, prefetch next tile's
    f32x4 av[4];
    int idj[4];
#pragma unroll
    for (int sub = 0; sub < 4; ++sub) { av[sub] = avn[sub]; idj[sub] = idjn[sub]; }
    if (jt + 1 < NT) {
#pragma unroll
      for (int sub = 0; sub < 4; ++sub) {
        avn[sub] = avrow[jb + 64 + sub * 16 + c];
        idjn[sub] = ids[jb + 64 + sub * 16 + c];
      }
    }

    // QK^T from LDS (swizzled reads: chunk wanted ^ (row&7), row&7 == c&7)
    const short* kbb = &kb_lds[cur][c * 64];
    const short* krb = &kr_lds[cur][c * 64];
    int co0 = (g ^ (c & 7)) * 8;
    int co1 = ((4 + g) ^ (c & 7)) * 8;
    f32x4 raw[4], rpe[4];
#pragma unroll
    for (int sub = 0; sub < 4; ++sub) {
      bf16x8 k0 = *(const bf16x8*)(kbb + sub * 1024 + co0);
      bf16x8 k1 = *(const bf16x8*)(kbb + sub * 1024 + co1);
      bf16x8 kr0 = *(const bf16x8*)(krb + sub * 1024 + co0);
      bf16x8 kr1 = *(const bf16x8*)(krb + sub * 1024 + co1);
      f32x4 z = (f32x4){0.f, 0.f, 0.f, 0.f};
      raw[sub] = MFMA(qA[1], k1, MFMA(qA[0], k0, z));
      rpe[sub] = MFMA(qrA[1], kr1, MFMA(qrA[0], kr0, z));
    }

    float t[4][4];
#pragma unroll
    for (int sub = 0; sub < 4; ++sub)
#pragma unroll
      for (int r = 0; r < 4; ++r) {
        float sv = (idi[r] == idj[sub]) ? rpe[sub][r] : (raw[sub][r] + av[sub][r]);
        t[sub][r] = sv * LOG2E;
      }

    // defer-max: only reduce/rescale when tile max approaches the bound
    float tm[4];
#pragma unroll
    for (int r = 0; r < 4; ++r)
      tm[r] = fmaxf(fmaxf(t[0][r], t[1][r]), fmaxf(t[2][r], t[3][r]));
    bool ok = (tm[0] <= mrun[0] + 8.f) && (tm[1] <= mrun[1] + 8.f) &&
              (tm[2] <= mrun[2] + 8.f) && (tm[3] <= mrun[3] + 8.f);
    if (!__all(ok)) {
#pragma unroll
      for (int r = 0; r < 4; ++r) {
        float m2 = tm[r];
#pragma unroll
        for (int d = 1; d < 16; d <<= 1) m2 = fmaxf(m2, __shfl_xor(m2, d));
        float mn = fmaxf(mrun[r], m2);
        float so = exp2f(mrun[r] - mn);
        mrun[r] = mn;
        lsum[r] *= so;
#pragma unroll
        for (int n = 0; n < 4; ++n) acc[n][r] *= so;
      }
    }

    // p = exp2(t - m), pack to LDS (wave-private tile; same-wave DS ordering)
#pragma unroll
    for (int sub = 0; sub < 4; ++sub)
#pragma unroll
      for (int r = 0; r < 4; ++r) {
        float p = exp2f(t[sub][r] - mrun[r]);
        lsum[r] += p;
        plds[w][g * 4 + r][sub * 16 + c] = f2bf(p);
      }

    // PV: two K=32 chunks with preloaded V fragments
    {
      bf16x8 pa = *(const bf16x8*)(&plds[w][c][g * 8]);
#pragma unroll
      for (int n = 0; n < 4; ++n) acc[n] = MFMA(pa, vf0[n], acc[n]);
      bf16x8 pb = *(const bf16x8*)(&plds[w][c][32 + g * 8]);
#pragma unroll
      for (int n = 0; n < 4; ++n) acc[n] = MFMA(pb, vf1[n], acc[n]);
    }

    __syncthreads();  // drains vmcnt (next tile staged) + guards LDS buffer swap
    cur ^= 1;
  }

  // cross-lane reduce of lsum (m already lane-uniform within group)
#pragma unroll
  for (int r = 0; r < 4; ++r) {
#pragma unroll
    for (int d = 1; d < 16; d <<= 1) lsum[r] += __shfl_xor(lsum[r], d);
  }
  size_t sb = (size_t)(sp * NH + h) * L;
  if (c == 0) {
#pragma unroll
    for (int r = 0; r < 4; ++r) {
      m_part[sb + i0 + g * 4 + r] = mrun[r];
      l_part[sb + i0 + g * 4 + r] = lsum[r];
    }
  }
#pragma unroll
  for (int n = 0; n < 4; ++n)
#pragma unroll
    for (int r = 0; r < 4; ++r)
      acc_part[(sb + i0 + g * 4 + r) * HD + n * 16 + c] = acc[n][r];
}

// ---------------------------------------------------------------- merge partials
__global__ void merge_kernel(const float* __restrict__ m_part,
                             const float* __restrict__ l_part,
                             const float* __restrict__ acc_part,
                             float* __restrict__ mfin, float* __restrict__ lfin,
                             short* __restrict__ attn_bf) {
  int idx = blockIdx.x * 256 + threadIdx.x;  // NH*L*HD
  int d = idx & (HD - 1);
  int hi = idx >> 6;          // h*L + i
  int i = hi & (L - 1), h = hi >> 11;
  float m4 = -3.0e38f;
#pragma unroll
  for (int s = 0; s < SPLIT; ++s)
    m4 = fmaxf(m4, m_part[(size_t)(s * NH + h) * L + i]);
  float l = 0.f, o = 0.f;
#pragma unroll
  for (int s = 0; s < SPLIT; ++s) {
    size_t sb = (size_t)(s * NH + h) * L + i;
    float e = exp2f(m_part[sb] - m4);
    l += l_part[sb] * e;
    o += acc_part[sb * HD + d] * e;
  }
  attn_bf[(size_t)i * D + h * HD + d] = f2bf(o / l);
  if (d == 0) { mfin[h * L + i] = m4; lfin[h * L + i] = l; }
}

// ---------------------------------------------------------------- probs mean (half the heads)
// grid (L/64 j, L/64 i, 2). Each block: 8 heads, 16x64 per wave; unscaled sum -> tmp.
__global__ __launch_bounds__(256) void pavg_kernel(
    const short* __restrict__ Qs, const short* __restrict__ Kb,
    const short* __restrict__ QR, const short* __restrict__ KR,
    const f32x4* __restrict__ avg4, const int* __restrict__ ids,
    const float* __restrict__ m_ws, const float* __restrict__ l_ws,
    float* __restrict__ tmp) {
  int j0 = blockIdx.x * 64;
  int iblk = blockIdx.y * 64;
  int hg = blockIdx.z;          // head group: heads hg*8 .. hg*8+7
  int h0 = hg * 8;
  int w = threadIdx.x >> 6, lane = threadIdx.x & 63;
  int c = lane & 15, g = lane >> 4;
  int i0 = iblk + w * 16;

  __shared__ float mS[8][64], lS[8][64];
  for (int idx = threadIdx.x; idx < 8 * 64; idx += 256) {
    int hh = idx >> 6, rr = idx & 63;
    mS[hh][rr] = m_ws[(h0 + hh) * L + iblk + rr];
    lS[hh][rr] = 1.0f / l_ws[(h0 + hh) * L + iblk + rr];
  }
  __syncthreads();

  int idi[4], idj[4];
  f32x4 av[4];
  {
    const f32x4* avrow = avg4 + (size_t)((i0 >> 2) + g) * L;
#pragma unroll
    for (int sub = 0; sub < 4; ++sub) {
      av[sub] = avrow[j0 + sub * 16 + c];
      idj[sub] = ids[j0 + sub * 16 + c];
    }
#pragma unroll
    for (int r = 0; r < 4; ++r) idi[r] = ids[i0 + g * 4 + r];
  }

  f32x4 psum[4];
#pragma unroll
  for (int sub = 0; sub < 4; ++sub) psum[sub] = (f32x4){0.f, 0.f, 0.f, 0.f};

  const short* qbase = Qs + (size_t)(i0 + c) * D + g * 8 + h0 * HD;
  const short* qrbase = QR + (size_t)(i0 + c) * D + g * 8 + h0 * HD;

  for (int hh = 0; hh < 8; ++hh) {
    int hk = hh * 64;
    // issue all 20 loads for this head up-front (independent -> deep MLP)
    bf16x8 q0 = *(const bf16x8*)(qbase + hk);
    bf16x8 q1 = *(const bf16x8*)(qbase + hk + 32);
    bf16x8 qr0 = *(const bf16x8*)(qrbase + hk);
    bf16x8 qr1 = *(const bf16x8*)(qrbase + hk + 32);
    bf16x8 kf[4][2], krf[4][2];
#pragma unroll
    for (int sub = 0; sub < 4; ++sub) {
      const short* kp = Kb + (size_t)(j0 + sub * 16 + c) * D + h0 * HD + hk + g * 8;
      const short* krp = KR + (size_t)(j0 + sub * 16 + c) * D + h0 * HD + hk + g * 8;
      kf[sub][0] = *(const bf16x8*)kp;
      kf[sub][1] = *(const bf16x8*)(kp + 32);
      krf[sub][0] = *(const bf16x8*)krp;
      krf[sub][1] = *(const bf16x8*)(krp + 32);
    }

    f32x4 raw[4], rpe[4];
#pragma unroll
    for (int sub = 0; sub < 4; ++sub) {
      f32x4 z = (f32x4){0.f, 0.f, 0.f, 0.f};
      f32x4 r0 = MFMA(q0, kf[sub][0], z);
      raw[sub] = MFMA(q1, kf[sub][1], r0);
      f32x4 r1 = MFMA(qr0, krf[sub][0], z);
      rpe[sub] = MFMA(qr1, krf[sub][1], r1);
    }

    f32x4 m4 = *(const f32x4*)(&mS[hh][w * 16 + g * 4]);
    f32x4 l4 = *(const f32x4*)(&lS[hh][w * 16 + g * 4]);
#pragma unroll
    for (int sub = 0; sub < 4; ++sub)
#pragma unroll
      for (int r = 0; r < 4; ++r) {
        float s = (idi[r] == idj[sub]) ? rpe[sub][r] : (raw[sub][r] + av[sub][r]);
        psum[sub][r] += exp2f(s * LOG2E - m4[r]) * l4[r];
      }
  }

  float* dst = tmp + (size_t)hg * L * L;
#pragma unroll
  for (int sub = 0; sub < 4; ++sub)
#pragma unroll
    for (int r = 0; r < 4; ++r)
      dst[(size_t)(i0 + g * 4 + r) * L + j0 + sub * 16 + c] = psum[sub][r];
}

// ---------------------------------------------------------------- add halves + scale
__global__ void addscale_kernel(const f32x4* __restrict__ a, const f32x4* __restrict__ b,
                                f32x4* __restrict__ out) {
  int i = blockIdx.x * 256 + threadIdx.x;  // L*L/4 total
  f32x4 v = a[i], u = b[i];
  f32x4 o;
#pragma unroll
  for (int r = 0; r < 4; ++r) o[r] = (v[r] + u[r]) * 0.0625f;
  out[i] = o;
}

// ---------------------------------------------------------------- out proj
__global__ __launch_bounds__(256) void outproj_kernel(
    const short* __restrict__ A, const short* __restrict__ W,
    const float* __restrict__ bias, float* __restrict__ out) {
  int w = threadIdx.x >> 6, lane = threadIdx.x & 63;
  int c = lane & 15, g = lane >> 4;
  int wi0 = blockIdx.y * 128 + (w >> 1) * 64;
  int wj0 = blockIdx.x * 128 + (w & 1) * 64;

  f32x4 acc[4][4];
#pragma unroll
  for (int m = 0; m < 4; ++m)
#pragma unroll
    for (int n = 0; n < 4; ++n) acc[m][n] = (f32x4){0.f, 0.f, 0.f, 0.f};

  for (int k0 = 0; k0 < D; k0 += 32) {
    bf16x8 aF[4], bF[4];
#pragma unroll
    for (int m = 0; m < 4; ++m)
      aF[m] = *(const bf16x8*)(A + (size_t)(wi0 + m * 16 + c) * D + k0 + g * 8);
#pragma unroll
    for (int n = 0; n < 4; ++n)
      bF[n] = *(const bf16x8*)(W + (size_t)(wj0 + n * 16 + c) * D + k0 + g * 8);
#pragma unroll
    for (int m = 0; m < 4; ++m)
#pragma unroll
      for (int n = 0; n < 4; ++n) acc[m][n] = MFMA(aF[m], bF[n], acc[m][n]);
  }

#pragma unroll
  for (int m = 0; m < 4; ++m)
#pragma unroll
    for (int n = 0; n < 4; ++n)
#pragma unroll
      for (int r = 0; r < 4; ++r) {
        int i = wi0 + m * 16 + g * 4 + r;
        int col = wj0 + n * 16 + c;
        out[(size_t)i * D + col] = acc[m][n][r] + bias[col];
      }
}

// ---------------------------------------------------------------- launch
extern "C" void kernel_launch(void* const* d_in, const int* in_sizes, int n_in,
                              void* d_out, int out_size, void* d_ws, size_t ws_size,
                              hipStream_t stream) {
  const float* query = (const float*)d_in[0];
  const int* ids = (const int*)d_in[1];
  const float* wq = (const float*)d_in[2];
  const float* bq = (const float*)d_in[3];
  const float* wk = (const float*)d_in[4];
  const float* bk = (const float*)d_in[5];
  const float* wv = (const float*)d_in[6];
  const float* bv = (const float*)d_in[7];
  const float* wo = (const float*)d_in[8];
  const float* bo = (const float*)d_in[9];

  char* p = (char*)d_ws;
  auto carve = [&](size_t bytes) {
    char* r = p;
    p += (bytes + 255) & ~(size_t)255;
    return r;
  };
  short* Xbf = (short*)carve((size_t)L * D * 2);
  short* Wqb = (short*)carve((size_t)D * D * 2);
  short* Wkb = (short*)carve((size_t)D * D * 2);
  short* Wvb = (short*)carve((size_t)D * D * 2);
  short* Wob = (short*)carve((size_t)D * D * 2);
  short* Qs = (short*)carve((size_t)L * D * 2);
  short* QRb = (short*)carve((size_t)L * D * 2);
  short* Kbb = (short*)carve((size_t)L * D * 2);
  short* KRb = (short*)carve((size_t)L * D * 2);
  short* Vt = (short*)carve((size_t)L * D * 2);
  f32x4* avg4 = (f32x4*)carve((size_t)L * L * 4);
  float* m_ws = (float*)carve((size_t)NH * L * 4);
  float* l_ws = (float*)carve((size_t)NH * L * 4);
  short* attn_bf = (short*)carve((size_t)L * D * 2);
  float* costab = (float*)carve((size_t)L * 32 * 4);
  float* sintab = (float*)carve((size_t)L * 32 * 4);
  float* m_part = (float*)carve((size_t)SPLIT * NH * L * 4);
  float* l_part = (float*)carve((size_t)SPLIT * NH * L * 4);
  float* acc_part = (float*)carve((size_t)SPLIT * NH * L * HD * 4);
  // pavg partial sums reuse acc_part (33.5 MB; consumed by merge_kernel before pavg)
  float* ptmp = acc_part;  // [2][L*L] floats = 33.5 MB

  float* out0 = (float*)d_out;                  // (L, 1, D)
  float* out1 = out0 + (size_t)L * D;           // (1, L, L)

  trig_kernel<<<(L * 32) / 256, 256, 0, stream>>>(costab, sintab);

  f2bf4_kernel<<<(L * D / 4 + 255) / 256, 256, 0, stream>>>(query, Xbf, L * D / 4);
  f2bf4_kernel<<<(D * D / 4 + 255) / 256, 256, 0, stream>>>(wq, Wqb, D * D / 4);
  f2bf4_kernel<<<(D * D / 4 + 255) / 256, 256, 0, stream>>>(wk, Wkb, D * D / 4);
  f2bf4_kernel<<<(D * D / 4 + 255) / 256, 256, 0, stream>>>(wv, Wvb, D * D / 4);
  f2bf4_kernel<<<(D * D / 4 + 255) / 256, 256, 0, stream>>>(wo, Wob, D * D / 4);

  dim3 gproj(D / 128, L / 128);
  proj_kernel<<<gproj, 256, 0, stream>>>(Xbf, Wqb, bq, costab, sintab, 0, Qs, QRb);
  proj_kernel<<<gproj, 256, 0, stream>>>(Xbf, Wkb, bk, costab, sintab, 1, Kbb, KRb);
  proj_kernel<<<gproj, 256, 0, stream>>>(Xbf, Wvb, bv, costab, sintab, 2, Vt, nullptr);

  avg_kernel<<<dim3(L / 128, L / 128), 256, 0, stream>>>(QRb, KRb, Qs, Kbb, avg4);

  flash3_kernel<<<dim3(L / 64, NH, SPLIT), 256, 0, stream>>>(
      Qs, Kbb, QRb, KRb, Vt, avg4, ids, m_part, l_part, acc_part);

  merge_kernel<<<(NH * L * HD) / 256, 256, 0, stream>>>(m_part, l_part, acc_part,
                                                        m_ws, l_ws, attn_bf);

  pavg_kernel<<<dim3(L / 64, L / 64, 2), 256, 0, stream>>>(
      Qs, Kbb, QRb, KRb, avg4, ids, m_ws, l_ws, ptmp);

  addscale_kernel<<<(L * L / 4) / 256, 256, 0, stream>>>(
      (const f32x4*)ptmp, (const f32x4*)(ptmp + (size_t)L * L), (f32x4*)out1);

  outproj_kernel<<<dim3(D / 128, L / 128), 256, 0, stream>>>(attn_bf, Wob, bo, out0);
}

// Round 7
// 445.945 us; speedup vs baseline: 1.1308x; 1.1308x over previous
//
#include <hip/hip_runtime.h>

#define L 2048
#define D 1024
#define NH 16
#define HD 64
#define SPLIT 4
#define JCH (L / SPLIT)
#define LOG2E 1.4426950408889634f

typedef __attribute__((ext_vector_type(8))) short bf16x8;
typedef __attribute__((ext_vector_type(4))) float f32x4;

#define MFMA(a, b, c) __builtin_amdgcn_mfma_f32_16x16x32_bf16(a, b, c, 0, 0, 0)

__device__ __forceinline__ short f2bf(float x) {
  unsigned u = __float_as_uint(x);
  u = (u + 0x7FFFu + ((u >> 16) & 1u)) >> 16;  // RNE
  return (short)u;
}

// async global->LDS, 16B per lane. LDS dest = wave-uniform base + lane*16.
__device__ __forceinline__ void gll16(const void* g, void* l) {
  __builtin_amdgcn_global_load_lds(
      (const __attribute__((address_space(1))) void*)(uintptr_t)g,
      (__attribute__((address_space(3))) void*)(unsigned)(uintptr_t)l, 16, 0, 0);
}

// ---------------------------------------------------------------- trig table
__global__ void trig_kernel(float* __restrict__ costab, float* __restrict__ sintab) {
  int idx = blockIdx.x * blockDim.x + threadIdx.x;  // 65536 total
  int t = idx >> 5, fi = idx & 31;
  float f = exp2f(-(float)fi * (13.287712379549449f / 32.0f));  // 10000^(-fi/32)
  float ang = (float)t * f;
  costab[idx] = cosf(ang);
  sintab[idx] = sinf(ang);
}

// ---------------------------------------------------------------- f32 -> bf16
__global__ void f2bf4_kernel(const float* __restrict__ in, short* __restrict__ out, int n4) {
  int i = blockIdx.x * blockDim.x + threadIdx.x;
  if (i < n4) {
    float4 v = ((const float4*)in)[i];
    short4 o;
    o.x = f2bf(v.x); o.y = f2bf(v.y); o.z = f2bf(v.z); o.w = f2bf(v.w);
    ((short4*)out)[i] = o;
  }
}

// ---------------------------------------------------------------- projection
__global__ __launch_bounds__(256) void proj_kernel(
    const short* __restrict__ X, const short* __restrict__ W,
    const float* __restrict__ bias, const float* __restrict__ costab,
    const float* __restrict__ sintab, int mode,
    short* __restrict__ out_main, short* __restrict__ out_rope) {
  int w = threadIdx.x >> 6, lane = threadIdx.x & 63;
  int c = lane & 15, g = lane >> 4;
  int wi0 = blockIdx.y * 128 + (w >> 1) * 64;
  int wj0 = blockIdx.x * 128 + (w & 1) * 64;

  f32x4 acc[4][4];
#pragma unroll
  for (int m = 0; m < 4; ++m)
#pragma unroll
    for (int n = 0; n < 4; ++n) acc[m][n] = (f32x4){0.f, 0.f, 0.f, 0.f};

  for (int k0 = 0; k0 < D; k0 += 32) {
    bf16x8 aF[4], bF[4];
#pragma unroll
    for (int m = 0; m < 4; ++m)
      aF[m] = *(const bf16x8*)(X + (size_t)(wi0 + m * 16 + c) * D + k0 + g * 8);
#pragma unroll
    for (int n = 0; n < 4; ++n)
      bF[n] = *(const bf16x8*)(W + (size_t)(wj0 + n * 16 + c) * D + k0 + g * 8);
#pragma unroll
    for (int m = 0; m < 4; ++m)
#pragma unroll
      for (int n = 0; n < 4; ++n) acc[m][n] = MFMA(aF[m], bF[n], acc[m][n]);
  }

  float scale = (mode == 0) ? 0.125f : 1.0f;
#pragma unroll
  for (int m = 0; m < 4; ++m) {
#pragma unroll
    for (int r = 0; r < 4; ++r) {
      int i = wi0 + m * 16 + g * 4 + r;
      float v4[4];
#pragma unroll
      for (int n = 0; n < 4; ++n)
        v4[n] = (acc[m][n][r] + bias[wj0 + n * 16 + c]) * scale;
      if (mode == 2) {
#pragma unroll
        for (int n = 0; n < 4; ++n) {
          int col = wj0 + n * 16 + c;
          out_main[(size_t)col * L + i] = f2bf(v4[n]);  // Vt[col][i]
        }
      } else {
#pragma unroll
        for (int n = 0; n < 4; ++n) {
          int col = wj0 + n * 16 + c;
          out_main[(size_t)i * D + col] = f2bf(v4[n]);
          float rot = (n < 2) ? -v4[n + 2] : v4[n - 2];
          int fidx = i * 32 + (n & 1) * 16 + c;
          float vr = v4[n] * costab[fidx] + rot * sintab[fidx];
          out_rope[(size_t)i * D + col] = f2bf(vr);
        }
      }
    }
  }
}

// ---------------------------------------------------------------- avg dual-GEMM
// avg4[((i>>2)*L + j)] = f32x4 over i&3 of (QR@KR^T - Qs@Kb^T)/16
__global__ __launch_bounds__(256) void avg_kernel(
    const short* __restrict__ QR, const short* __restrict__ KR,
    const short* __restrict__ Qs, const short* __restrict__ Kb,
    f32x4* __restrict__ avg4) {
  int w = threadIdx.x >> 6, lane = threadIdx.x & 63;
  int c = lane & 15, g = lane >> 4;
  int wi0 = blockIdx.y * 128 + (w >> 1) * 64;
  int wj0 = blockIdx.x * 128 + (w & 1) * 64;

  f32x4 acc1[4][4], acc2[4][4];
#pragma unroll
  for (int m = 0; m < 4; ++m)
#pragma unroll
    for (int n = 0; n < 4; ++n) {
      acc1[m][n] = (f32x4){0.f, 0.f, 0.f, 0.f};
      acc2[m][n] = (f32x4){0.f, 0.f, 0.f, 0.f};
    }

  for (int k0 = 0; k0 < D; k0 += 32) {
    bf16x8 aF[4], bF[4], a2F[4], b2F[4];
#pragma unroll
    for (int m = 0; m < 4; ++m) {
      aF[m] = *(const bf16x8*)(QR + (size_t)(wi0 + m * 16 + c) * D + k0 + g * 8);
      a2F[m] = *(const bf16x8*)(Qs + (size_t)(wi0 + m * 16 + c) * D + k0 + g * 8);
    }
#pragma unroll
    for (int n = 0; n < 4; ++n) {
      bF[n] = *(const bf16x8*)(KR + (size_t)(wj0 + n * 16 + c) * D + k0 + g * 8);
      b2F[n] = *(const bf16x8*)(Kb + (size_t)(wj0 + n * 16 + c) * D + k0 + g * 8);
    }
#pragma unroll
    for (int m = 0; m < 4; ++m)
#pragma unroll
      for (int n = 0; n < 4; ++n) {
        acc1[m][n] = MFMA(aF[m], bF[n], acc1[m][n]);
        acc2[m][n] = MFMA(a2F[m], b2F[n], acc2[m][n]);
      }
  }

#pragma unroll
  for (int m = 0; m < 4; ++m)
#pragma unroll
    for (int n = 0; n < 4; ++n) {
      int j = wj0 + n * 16 + c;
      f32x4 o;
#pragma unroll
      for (int r = 0; r < 4; ++r) o[r] = (acc1[m][n][r] - acc2[m][n][r]) * 0.0625f;
      avg4[(size_t)(((wi0 + m * 16) >> 2) + g) * L + j] = o;
    }
}

// ---------------------------------------------------------------- single-pass flash, KV-split
// grid (L/64, NH, SPLIT). 4 waves, 16 rows each. K/KR tiles staged in LDS via
// global_load_lds (async, double-buffered, XOR-swizzled); V direct from global.
__global__ __launch_bounds__(256) void flash3_kernel(
    const short* __restrict__ Qs, const short* __restrict__ Kb,
    const short* __restrict__ QR, const short* __restrict__ KR,
    const short* __restrict__ Vt, const f32x4* __restrict__ avg4,
    const int* __restrict__ ids, float* __restrict__ m_part,
    float* __restrict__ l_part, float* __restrict__ acc_part) {
  int h = blockIdx.y, sp = blockIdx.z;
  int w = threadIdx.x >> 6, lane = threadIdx.x & 63;
  int c = lane & 15, g = lane >> 4;
  int i0 = blockIdx.x * 64 + w * 16;
  int hk = h * 64;

  // [2 buf][64 rows][64 shorts]; 16B chunk at (row, ch) holds global chunk ch^(row&7)
  __shared__ short kb_lds[2][64 * 64];
  __shared__ short kr_lds[2][64 * 64];
  __shared__ short plds[4][16][72];

  // staging: wave w covers rows w*16..w*16+15 per subtile; lane l -> dest row
  // r0+ (l>>3), dest chunk l&7, source chunk (l&7)^(l>>3)  (r0 % 8 == 0)
  int srow = lane >> 3;
  int sxor = (lane & 7) ^ srow;
  int r0a = w * 16, r0b = w * 16 + 8;

  bf16x8 qA[2], qrA[2];
  {
    const short* qp = Qs + (size_t)(i0 + c) * D + hk + g * 8;
    const short* qrp = QR + (size_t)(i0 + c) * D + hk + g * 8;
    qA[0] = *(const bf16x8*)qp;   qA[1] = *(const bf16x8*)(qp + 32);
    qrA[0] = *(const bf16x8*)qrp; qrA[1] = *(const bf16x8*)(qrp + 32);
  }

  int idi[4];
  float mrun[4], lsum[4];
  f32x4 acc[4];
#pragma unroll
  for (int r = 0; r < 4; ++r) {
    idi[r] = ids[i0 + g * 4 + r];
    mrun[r] = -3.0e38f;
    lsum[r] = 0.f;
  }
#pragma unroll
  for (int n = 0; n < 4; ++n) acc[n] = (f32x4){0.f, 0.f, 0.f, 0.f};

  const f32x4* avrow = avg4 + (size_t)((i0 >> 2) + g) * L;
  int jbase = sp * JCH;
  const int NT = JCH / 64;

  // prologue: stage tile 0 + prefetch tile 0 avg/ids
  gll16(Kb + (size_t)(jbase + r0a + srow) * D + hk + sxor * 8, &kb_lds[0][r0a * 64]);
  gll16(Kb + (size_t)(jbase + r0b + srow) * D + hk + sxor * 8, &kb_lds[0][r0b * 64]);
  gll16(KR + (size_t)(jbase + r0a + srow) * D + hk + sxor * 8, &kr_lds[0][r0a * 64]);
  gll16(KR + (size_t)(jbase + r0b + srow) * D + hk + sxor * 8, &kr_lds[0][r0b * 64]);

  f32x4 avn[4];
  int idjn[4];
#pragma unroll
  for (int sub = 0; sub < 4; ++sub) {
    avn[sub] = avrow[jbase + sub * 16 + c];
    idjn[sub] = ids[jbase + sub * 16 + c];
  }
  __syncthreads();  // drains vmcnt -> tile 0 staged

  int cur = 0;
  for (int jt = 0; jt < NT; ++jt) {
    int jb = jbase + jt * 64;

    // issue next tile's staging (in flight during this tile's compute)
    if (jt + 1 < NT) {
      int jn = jb + 64;
      short* kd = &kb_lds[cur ^ 1][0];
      short* rd = &kr_lds[cur ^ 1][0];
      gll16(Kb + (size_t)(jn + r0a + srow) * D + hk + sxor * 8, kd + r0a * 64);
      gll16(Kb + (size_t)(jn + r0b + srow) * D + hk + sxor * 8, kd + r0b * 64);
      gll16(KR + (size_t)(jn + r0a + srow) * D + hk + sxor * 8, rd + r0a * 64);
      gll16(KR + (size_t)(jn + r0b + srow) * D + hk + sxor * 8, rd + r0b * 64);
    }

    // V loads early (consumed at PV, covered by QK+softmax)
    bf16x8 vf0[4], vf1[4];
#pragma unroll
    for (int n = 0; n < 4; ++n) {
      const short* vp = Vt + (size_t)(hk + n * 16 + c) * L + jb + g * 8;
      vf0[n] = *(const bf16x8*)vp;
      vf1[n] = *(const bf16x8*)(vp + 32);
    }

    // rotate avg/ids, prefetch next tile's
    f32x4 av[4];
    int idj[4];
#pragma unroll
    for (int sub = 0; sub < 4; ++sub) { av[sub] = avn[sub]; idj[sub] = idjn[sub]; }
    if (jt + 1 < NT) {
#pragma unroll
      for (int sub = 0; sub < 4; ++sub) {
        avn[sub] = avrow[jb + 64 + sub * 16 + c];
        idjn[sub] = ids[jb + 64 + sub * 16 + c];
      }
    }

    // QK^T from LDS (swizzled reads: chunk wanted ^ (row&7), row&7 == c&7)
    const short* kbb = &kb_lds[cur][c * 64];
    const short* krb = &kr_lds[cur][c * 64];
    int co0 = (g ^ (c & 7)) * 8;
    int co1 = ((4 + g) ^ (c & 7)) * 8;
    f32x4 raw[4], rpe[4];
#pragma unroll
    for (int sub = 0; sub < 4; ++sub) {
      bf16x8 k0 = *(const bf16x8*)(kbb + sub * 1024 + co0);
      bf16x8 k1 = *(const bf16x8*)(kbb + sub * 1024 + co1);
      bf16x8 kr0 = *(const bf16x8*)(krb + sub * 1024 + co0);
      bf16x8 kr1 = *(const bf16x8*)(krb + sub * 1024 + co1);
      f32x4 z = (f32x4){0.f, 0.f, 0.f, 0.f};
      raw[sub] = MFMA(qA[1], k1, MFMA(qA[0], k0, z));
      rpe[sub] = MFMA(qrA[1], kr1, MFMA(qrA[0], kr0, z));
    }

    float t[4][4];
#pragma unroll
    for (int sub = 0; sub < 4; ++sub)
#pragma unroll
      for (int r = 0; r < 4; ++r) {
        float sv = (idi[r] == idj[sub]) ? rpe[sub][r] : (raw[sub][r] + av[sub][r]);
        t[sub][r] = sv * LOG2E;
      }

    // defer-max: only reduce/rescale when tile max approaches the bound
    float tm[4];
#pragma unroll
    for (int r = 0; r < 4; ++r)
      tm[r] = fmaxf(fmaxf(t[0][r], t[1][r]), fmaxf(t[2][r], t[3][r]));
    bool ok = (tm[0] <= mrun[0] + 8.f) && (tm[1] <= mrun[1] + 8.f) &&
              (tm[2] <= mrun[2] + 8.f) && (tm[3] <= mrun[3] + 8.f);
    if (!__all(ok)) {
#pragma unroll
      for (int r = 0; r < 4; ++r) {
        float m2 = tm[r];
#pragma unroll
        for (int d = 1; d < 16; d <<= 1) m2 = fmaxf(m2, __shfl_xor(m2, d));
        float mn = fmaxf(mrun[r], m2);
        float so = exp2f(mrun[r] - mn);
        mrun[r] = mn;
        lsum[r] *= so;
#pragma unroll
        for (int n = 0; n < 4; ++n) acc[n][r] *= so;
      }
    }

    // p = exp2(t - m), pack to LDS (wave-private tile; same-wave DS ordering)
#pragma unroll
    for (int sub = 0; sub < 4; ++sub)
#pragma unroll
      for (int r = 0; r < 4; ++r) {
        float p = exp2f(t[sub][r] - mrun[r]);
        lsum[r] += p;
        plds[w][g * 4 + r][sub * 16 + c] = f2bf(p);
      }

    // PV: two K=32 chunks with preloaded V fragments
    {
      bf16x8 pa = *(const bf16x8*)(&plds[w][c][g * 8]);
#pragma unroll
      for (int n = 0; n < 4; ++n) acc[n] = MFMA(pa, vf0[n], acc[n]);
      bf16x8 pb = *(const bf16x8*)(&plds[w][c][32 + g * 8]);
#pragma unroll
      for (int n = 0; n < 4; ++n) acc[n] = MFMA(pb, vf1[n], acc[n]);
    }

    __syncthreads();  // drains vmcnt (next tile staged) + guards LDS buffer swap
    cur ^= 1;
  }

  // cross-lane reduce of lsum (m already lane-uniform within group)
#pragma unroll
  for (int r = 0; r < 4; ++r) {
#pragma unroll
    for (int d = 1; d < 16; d <<= 1) lsum[r] += __shfl_xor(lsum[r], d);
  }
  size_t sb = (size_t)(sp * NH + h) * L;
  if (c == 0) {
#pragma unroll
    for (int r = 0; r < 4; ++r) {
      m_part[sb + i0 + g * 4 + r] = mrun[r];
      l_part[sb + i0 + g * 4 + r] = lsum[r];
    }
  }
#pragma unroll
  for (int n = 0; n < 4; ++n)
#pragma unroll
    for (int r = 0; r < 4; ++r)
      acc_part[(sb + i0 + g * 4 + r) * HD + n * 16 + c] = acc[n][r];
}

// ---------------------------------------------------------------- merge partials
__global__ void merge_kernel(const float* __restrict__ m_part,
                             const float* __restrict__ l_part,
                             const float* __restrict__ acc_part,
                             float* __restrict__ mfin, float* __restrict__ lfin,
                             short* __restrict__ attn_bf) {
  int idx = blockIdx.x * 256 + threadIdx.x;  // NH*L*HD
  int d = idx & (HD - 1);
  int hi = idx >> 6;          // h*L + i
  int i = hi & (L - 1), h = hi >> 11;
  float m4 = -3.0e38f;
#pragma unroll
  for (int s = 0; s < SPLIT; ++s)
    m4 = fmaxf(m4, m_part[(size_t)(s * NH + h) * L + i]);
  float l = 0.f, o = 0.f;
#pragma unroll
  for (int s = 0; s < SPLIT; ++s) {
    size_t sb = (size_t)(s * NH + h) * L + i;
    float e = exp2f(m_part[sb] - m4);
    l += l_part[sb] * e;
    o += acc_part[sb * HD + d] * e;
  }
  attn_bf[(size_t)i * D + h * HD + d] = f2bf(o / l);
  if (d == 0) { mfin[h * L + i] = m4; lfin[h * L + i] = l; }
}

// ---------------------------------------------------------------- probs mean
// grid (L/64 j, L/64 i). 4 waves; 16 rows x 64 cols each. K/KR head-tiles staged
// in LDS (double-buffered, XOR-swizzled, head-ahead prefetch); Q pipelined in regs.
__global__ __launch_bounds__(256) void pavg_kernel(
    const short* __restrict__ Qs, const short* __restrict__ Kb,
    const short* __restrict__ QR, const short* __restrict__ KR,
    const f32x4* __restrict__ avg4, const int* __restrict__ ids,
    const float* __restrict__ m_ws, const float* __restrict__ l_ws,
    float* __restrict__ out1) {
  int j0 = blockIdx.x * 64;
  int iblk = blockIdx.y * 64;
  int w = threadIdx.x >> 6, lane = threadIdx.x & 63;
  int c = lane & 15, g = lane >> 4;
  int i0 = iblk + w * 16;

  __shared__ short kb_lds[2][64 * 64];
  __shared__ short kr_lds[2][64 * 64];
  __shared__ float mS[NH][64], lS[NH][64];

  // staging geometry (same as flash3): LDS[row][ch] = global[row][ch^(row&7)]
  int srow = lane >> 3;
  int sxor = (lane & 7) ^ srow;
  int r0a = w * 16, r0b = w * 16 + 8;

  for (int idx = threadIdx.x; idx < NH * 64; idx += 256) {
    int hh = idx >> 6, rr = idx & 63;
    mS[hh][rr] = m_ws[hh * L + iblk + rr];
    lS[hh][rr] = 1.0f / l_ws[hh * L + iblk + rr];
  }

  // stage head 0 K/KR tiles
  gll16(Kb + (size_t)(j0 + r0a + srow) * D + sxor * 8, &kb_lds[0][r0a * 64]);
  gll16(Kb + (size_t)(j0 + r0b + srow) * D + sxor * 8, &kb_lds[0][r0b * 64]);
  gll16(KR + (size_t)(j0 + r0a + srow) * D + sxor * 8, &kr_lds[0][r0a * 64]);
  gll16(KR + (size_t)(j0 + r0b + srow) * D + sxor * 8, &kr_lds[0][r0b * 64]);

  int idi[4], idj[4];
  f32x4 av[4];
  {
    const f32x4* avrow = avg4 + (size_t)((i0 >> 2) + g) * L;
#pragma unroll
    for (int sub = 0; sub < 4; ++sub) {
      av[sub] = avrow[j0 + sub * 16 + c];
      idj[sub] = ids[j0 + sub * 16 + c];
    }
#pragma unroll
    for (int r = 0; r < 4; ++r) idi[r] = ids[i0 + g * 4 + r];
  }

  f32x4 psum[4];
#pragma unroll
  for (int sub = 0; sub < 4; ++sub) psum[sub] = (f32x4){0.f, 0.f, 0.f, 0.f};

  const short* qbase = Qs + (size_t)(i0 + c) * D + g * 8;
  const short* qrbase = QR + (size_t)(i0 + c) * D + g * 8;

  // prefetch head 0 Q fragments
  bf16x8 nq0 = *(const bf16x8*)qbase, nq1 = *(const bf16x8*)(qbase + 32);
  bf16x8 nqr0 = *(const bf16x8*)qrbase, nqr1 = *(const bf16x8*)(qrbase + 32);

  __syncthreads();  // drains vmcnt -> head 0 staged; mS/lS ready

  int cur = 0;
#pragma unroll
  for (int hh = 0; hh < NH; ++hh) {
    // issue next head's K staging (in flight during this head's compute)
    if (hh + 1 < NH) {
      int hkn = (hh + 1) * 64;
      short* kd = &kb_lds[cur ^ 1][0];
      short* rd = &kr_lds[cur ^ 1][0];
      gll16(Kb + (size_t)(j0 + r0a + srow) * D + hkn + sxor * 8, kd + r0a * 64);
      gll16(Kb + (size_t)(j0 + r0b + srow) * D + hkn + sxor * 8, kd + r0b * 64);
      gll16(KR + (size_t)(j0 + r0a + srow) * D + hkn + sxor * 8, rd + r0a * 64);
      gll16(KR + (size_t)(j0 + r0b + srow) * D + hkn + sxor * 8, rd + r0b * 64);
    }

    // rotate Q, prefetch next head's Q
    bf16x8 q0 = nq0, q1 = nq1, qr0 = nqr0, qr1 = nqr1;
    if (hh + 1 < NH) {
      int hkn = (hh + 1) * 64;
      nq0 = *(const bf16x8*)(qbase + hkn);
      nq1 = *(const bf16x8*)(qbase + hkn + 32);
      nqr0 = *(const bf16x8*)(qrbase + hkn);
      nqr1 = *(const bf16x8*)(qrbase + hkn + 32);
    }

    // QK^T from LDS (swizzled reads)
    const short* kbb = &kb_lds[cur][c * 64];
    const short* krb = &kr_lds[cur][c * 64];
    int co0 = (g ^ (c & 7)) * 8;
    int co1 = ((4 + g) ^ (c & 7)) * 8;
    f32x4 raw[4], rpe[4];
#pragma unroll
    for (int sub = 0; sub < 4; ++sub) {
      bf16x8 k0 = *(const bf16x8*)(kbb + sub * 1024 + co0);
      bf16x8 k1 = *(const bf16x8*)(kbb + sub * 1024 + co1);
      bf16x8 kr0 = *(const bf16x8*)(krb + sub * 1024 + co0);
      bf16x8 kr1 = *(const bf16x8*)(krb + sub * 1024 + co1);
      f32x4 z = (f32x4){0.f, 0.f, 0.f, 0.f};
      raw[sub] = MFMA(q1, k1, MFMA(q0, k0, z));
      rpe[sub] = MFMA(qr1, kr1, MFMA(qr0, kr0, z));
    }

    f32x4 m4 = *(const f32x4*)(&mS[hh][w * 16 + g * 4]);
    f32x4 l4 = *(const f32x4*)(&lS[hh][w * 16 + g * 4]);
#pragma unroll
    for (int sub = 0; sub < 4; ++sub)
#pragma unroll
      for (int r = 0; r < 4; ++r) {
        float s = (idi[r] == idj[sub]) ? rpe[sub][r] : (raw[sub][r] + av[sub][r]);
        psum[sub][r] += exp2f(s * LOG2E - m4[r]) * l4[r];
      }

    __syncthreads();  // next head staged + guards LDS buffer swap
    cur ^= 1;
  }

#pragma unroll
  for (int sub = 0; sub < 4; ++sub)
#pragma unroll
    for (int r = 0; r < 4; ++r)
      out1[(size_t)(i0 + g * 4 + r) * L + j0 + sub * 16 + c] = psum[sub][r] * 0.0625f;
}

// ---------------------------------------------------------------- out proj
__global__ __launch_bounds__(256) void outproj_kernel(
    const short* __restrict__ A, const short* __restrict__ W,
    const float* __restrict__ bias, float* __restrict__ out) {
  int w = threadIdx.x >> 6, lane = threadIdx.x & 63;
  int c = lane & 15, g = lane >> 4;
  int wi0 = blockIdx.y * 128 + (w >> 1) * 64;
  int wj0 = blockIdx.x * 128 + (w & 1) * 64;

  f32x4 acc[4][4];
#pragma unroll
  for (int m = 0; m < 4; ++m)
#pragma unroll
    for (int n = 0; n < 4; ++n) acc[m][n] = (f32x4){0.f, 0.f, 0.f, 0.f};

  for (int k0 = 0; k0 < D; k0 += 32) {
    bf16x8 aF[4], bF[4];
#pragma unroll
    for (int m = 0; m < 4; ++m)
      aF[m] = *(const bf16x8*)(A + (size_t)(wi0 + m * 16 + c) * D + k0 + g * 8);
#pragma unroll
    for (int n = 0; n < 4; ++n)
      bF[n] = *(const bf16x8*)(W + (size_t)(wj0 + n * 16 + c) * D + k0 + g * 8);
#pragma unroll
    for (int m = 0; m < 4; ++m)
#pragma unroll
      for (int n = 0; n < 4; ++n) acc[m][n] = MFMA(aF[m], bF[n], acc[m][n]);
  }

#pragma unroll
  for (int m = 0; m < 4; ++m)
#pragma unroll
    for (int n = 0; n < 4; ++n)
#pragma unroll
      for (int r = 0; r < 4; ++r) {
        int i = wi0 + m * 16 + g * 4 + r;
        int col = wj0 + n * 16 + c;
        out[(size_t)i * D + col] = acc[m][n][r] + bias[col];
      }
}

// ---------------------------------------------------------------- launch
extern "C" void kernel_launch(void* const* d_in, const int* in_sizes, int n_in,
                              void* d_out, int out_size, void* d_ws, size_t ws_size,
                              hipStream_t stream) {
  const float* query = (const float*)d_in[0];
  const int* ids = (const int*)d_in[1];
  const float* wq = (const float*)d_in[2];
  const float* bq = (const float*)d_in[3];
  const float* wk = (const float*)d_in[4];
  const float* bk = (const float*)d_in[5];
  const float* wv = (const float*)d_in[6];
  const float* bv = (const float*)d_in[7];
  const float* wo = (const float*)d_in[8];
  const float* bo = (const float*)d_in[9];

  char* p = (char*)d_ws;
  auto carve = [&](size_t bytes) {
    char* r = p;
    p += (bytes + 255) & ~(size_t)255;
    return r;
  };
  short* Xbf = (short*)carve((size_t)L * D * 2);
  short* Wqb = (short*)carve((size_t)D * D * 2);
  short* Wkb = (short*)carve((size_t)D * D * 2);
  short* Wvb = (short*)carve((size_t)D * D * 2);
  short* Wob = (short*)carve((size_t)D * D * 2);
  short* Qs = (short*)carve((size_t)L * D * 2);
  short* QRb = (short*)carve((size_t)L * D * 2);
  short* Kbb = (short*)carve((size_t)L * D * 2);
  short* KRb = (short*)carve((size_t)L * D * 2);
  short* Vt = (short*)carve((size_t)L * D * 2);
  f32x4* avg4 = (f32x4*)carve((size_t)L * L * 4);
  float* m_ws = (float*)carve((size_t)NH * L * 4);
  float* l_ws = (float*)carve((size_t)NH * L * 4);
  short* attn_bf = (short*)carve((size_t)L * D * 2);
  float* costab = (float*)carve((size_t)L * 32 * 4);
  float* sintab = (float*)carve((size_t)L * 32 * 4);
  float* m_part = (float*)carve((size_t)SPLIT * NH * L * 4);
  float* l_part = (float*)carve((size_t)SPLIT * NH * L * 4);
  float* acc_part = (float*)carve((size_t)SPLIT * NH * L * HD * 4);

  float* out0 = (float*)d_out;                  // (L, 1, D)
  float* out1 = out0 + (size_t)L * D;           // (1, L, L)

  trig_kernel<<<(L * 32) / 256, 256, 0, stream>>>(costab, sintab);

  f2bf4_kernel<<<(L * D / 4 + 255) / 256, 256, 0, stream>>>(query, Xbf, L * D / 4);
  f2bf4_kernel<<<(D * D / 4 + 255) / 256, 256, 0, stream>>>(wq, Wqb, D * D / 4);
  f2bf4_kernel<<<(D * D / 4 + 255) / 256, 256, 0, stream>>>(wk, Wkb, D * D / 4);
  f2bf4_kernel<<<(D * D / 4 + 255) / 256, 256, 0, stream>>>(wv, Wvb, D * D / 4);
  f2bf4_kernel<<<(D * D / 4 + 255) / 256, 256, 0, stream>>>(wo, Wob, D * D / 4);

  dim3 gproj(D / 128, L / 128);
  proj_kernel<<<gproj, 256, 0, stream>>>(Xbf, Wqb, bq, costab, sintab, 0, Qs, QRb);
  proj_kernel<<<gproj, 256, 0, stream>>>(Xbf, Wkb, bk, costab, sintab, 1, Kbb, KRb);
  proj_kernel<<<gproj, 256, 0, stream>>>(Xbf, Wvb, bv, costab, sintab, 2, Vt, nullptr);

  avg_kernel<<<dim3(L / 128, L / 128), 256, 0, stream>>>(QRb, KRb, Qs, Kbb, avg4);

  flash3_kernel<<<dim3(L / 64, NH, SPLIT), 256, 0, stream>>>(
      Qs, Kbb, QRb, KRb, Vt, avg4, ids, m_part, l_part, acc_part);

  merge_kernel<<<(NH * L * HD) / 256, 256, 0, stream>>>(m_part, l_part, acc_part,
                                                        m_ws, l_ws, attn_bf);

  pavg_kernel<<<dim3(L / 64, L / 64), 256, 0, stream>>>(Qs, Kbb, QRb, KRb, avg4, ids,
                                                        m_ws, l_ws, out1);

  outproj_kernel<<<dim3(D / 128, L / 128), 256, 0, stream>>>(attn_bf, Wob, bo, out0);
}

// Round 8
// 402.699 us; speedup vs baseline: 1.2522x; 1.1074x over previous
//
#include <hip/hip_runtime.h>

#define L 2048
#define D 1024
#define NH 16
#define HD 64
#define SPLIT 4
#define JCH (L / SPLIT)
#define LOG2E 1.4426950408889634f

typedef __attribute__((ext_vector_type(8))) short bf16x8;
typedef __attribute__((ext_vector_type(4))) float f32x4;

#define MFMA(a, b, c) __builtin_amdgcn_mfma_f32_16x16x32_bf16(a, b, c, 0, 0, 0)

__device__ __forceinline__ short f2bf(float x) {
  unsigned u = __float_as_uint(x);
  u = (u + 0x7FFFu + ((u >> 16) & 1u)) >> 16;  // RNE
  return (short)u;
}

// async global->LDS, 16B per lane. LDS dest = wave-uniform base + lane*16.
__device__ __forceinline__ void gll16(const void* g, void* l) {
  __builtin_amdgcn_global_load_lds(
      (const __attribute__((address_space(1))) void*)(uintptr_t)g,
      (__attribute__((address_space(3))) void*)(unsigned)(uintptr_t)l, 16, 0, 0);
}

// ---------------------------------------------------------------- trig table
__global__ void trig_kernel(float* __restrict__ costab, float* __restrict__ sintab) {
  int idx = blockIdx.x * blockDim.x + threadIdx.x;  // 65536 total
  int t = idx >> 5, fi = idx & 31;
  float f = exp2f(-(float)fi * (13.287712379549449f / 32.0f));  // 10000^(-fi/32)
  float ang = (float)t * f;
  costab[idx] = cosf(ang);
  sintab[idx] = sinf(ang);
}

// ---------------------------------------------------------------- f32 -> bf16
__global__ void f2bf4_kernel(const float* __restrict__ in, short* __restrict__ out, int n4) {
  int i = blockIdx.x * blockDim.x + threadIdx.x;
  if (i < n4) {
    float4 v = ((const float4*)in)[i];
    short4 o;
    o.x = f2bf(v.x); o.y = f2bf(v.y); o.z = f2bf(v.z); o.w = f2bf(v.w);
    ((short4*)out)[i] = o;
  }
}

// ---------------------------------------------------------------- projection
__global__ __launch_bounds__(256) void proj_kernel(
    const short* __restrict__ X, const short* __restrict__ W,
    const float* __restrict__ bias, const float* __restrict__ costab,
    const float* __restrict__ sintab, int mode,
    short* __restrict__ out_main, short* __restrict__ out_rope) {
  int w = threadIdx.x >> 6, lane = threadIdx.x & 63;
  int c = lane & 15, g = lane >> 4;
  int wi0 = blockIdx.y * 128 + (w >> 1) * 64;
  int wj0 = blockIdx.x * 128 + (w & 1) * 64;

  f32x4 acc[4][4];
#pragma unroll
  for (int m = 0; m < 4; ++m)
#pragma unroll
    for (int n = 0; n < 4; ++n) acc[m][n] = (f32x4){0.f, 0.f, 0.f, 0.f};

  for (int k0 = 0; k0 < D; k0 += 32) {
    bf16x8 aF[4], bF[4];
#pragma unroll
    for (int m = 0; m < 4; ++m)
      aF[m] = *(const bf16x8*)(X + (size_t)(wi0 + m * 16 + c) * D + k0 + g * 8);
#pragma unroll
    for (int n = 0; n < 4; ++n)
      bF[n] = *(const bf16x8*)(W + (size_t)(wj0 + n * 16 + c) * D + k0 + g * 8);
#pragma unroll
    for (int m = 0; m < 4; ++m)
#pragma unroll
      for (int n = 0; n < 4; ++n) acc[m][n] = MFMA(aF[m], bF[n], acc[m][n]);
  }

  float scale = (mode == 0) ? 0.125f : 1.0f;
#pragma unroll
  for (int m = 0; m < 4; ++m) {
#pragma unroll
    for (int r = 0; r < 4; ++r) {
      int i = wi0 + m * 16 + g * 4 + r;
      float v4[4];
#pragma unroll
      for (int n = 0; n < 4; ++n)
        v4[n] = (acc[m][n][r] + bias[wj0 + n * 16 + c]) * scale;
      if (mode == 2) {
#pragma unroll
        for (int n = 0; n < 4; ++n) {
          int col = wj0 + n * 16 + c;
          out_main[(size_t)col * L + i] = f2bf(v4[n]);  // Vt[col][i]
        }
      } else {
#pragma unroll
        for (int n = 0; n < 4; ++n) {
          int col = wj0 + n * 16 + c;
          out_main[(size_t)i * D + col] = f2bf(v4[n]);
          float rot = (n < 2) ? -v4[n + 2] : v4[n - 2];
          int fidx = i * 32 + (n & 1) * 16 + c;
          float vr = v4[n] * costab[fidx] + rot * sintab[fidx];
          out_rope[(size_t)i * D + col] = f2bf(vr);
        }
      }
    }
  }
}

// ---------------------------------------------------------------- avg dual-GEMM
// avg4[((i>>2)*L + j)] = f32x4 over i&3 of (QR@KR^T - Qs@Kb^T)/16
__global__ __launch_bounds__(256) void avg_kernel(
    const short* __restrict__ QR, const short* __restrict__ KR,
    const short* __restrict__ Qs, const short* __restrict__ Kb,
    f32x4* __restrict__ avg4) {
  int w = threadIdx.x >> 6, lane = threadIdx.x & 63;
  int c = lane & 15, g = lane >> 4;
  int wi0 = blockIdx.y * 128 + (w >> 1) * 64;
  int wj0 = blockIdx.x * 128 + (w & 1) * 64;

  f32x4 acc1[4][4], acc2[4][4];
#pragma unroll
  for (int m = 0; m < 4; ++m)
#pragma unroll
    for (int n = 0; n < 4; ++n) {
      acc1[m][n] = (f32x4){0.f, 0.f, 0.f, 0.f};
      acc2[m][n] = (f32x4){0.f, 0.f, 0.f, 0.f};
    }

  for (int k0 = 0; k0 < D; k0 += 32) {
    bf16x8 aF[4], bF[4], a2F[4], b2F[4];
#pragma unroll
    for (int m = 0; m < 4; ++m) {
      aF[m] = *(const bf16x8*)(QR + (size_t)(wi0 + m * 16 + c) * D + k0 + g * 8);
      a2F[m] = *(const bf16x8*)(Qs + (size_t)(wi0 + m * 16 + c) * D + k0 + g * 8);
    }
#pragma unroll
    for (int n = 0; n < 4; ++n) {
      bF[n] = *(const bf16x8*)(KR + (size_t)(wj0 + n * 16 + c) * D + k0 + g * 8);
      b2F[n] = *(const bf16x8*)(Kb + (size_t)(wj0 + n * 16 + c) * D + k0 + g * 8);
    }
#pragma unroll
    for (int m = 0; m < 4; ++m)
#pragma unroll
      for (int n = 0; n < 4; ++n) {
        acc1[m][n] = MFMA(aF[m], bF[n], acc1[m][n]);
        acc2[m][n] = MFMA(a2F[m], b2F[n], acc2[m][n]);
      }
  }

#pragma unroll
  for (int m = 0; m < 4; ++m)
#pragma unroll
    for (int n = 0; n < 4; ++n) {
      int j = wj0 + n * 16 + c;
      f32x4 o;
#pragma unroll
      for (int r = 0; r < 4; ++r) o[r] = (acc1[m][n][r] - acc2[m][n][r]) * 0.0625f;
      avg4[(size_t)(((wi0 + m * 16) >> 2) + g) * L + j] = o;
    }
}

// ---------------------------------------------------------------- single-pass flash, KV-split
// grid (L/64, NH, SPLIT). 4 waves, 16 rows each. K/KR tiles staged in LDS via
// global_load_lds (async, double-buffered, XOR-swizzled); V direct from global.
__global__ __launch_bounds__(256) void flash3_kernel(
    const short* __restrict__ Qs, const short* __restrict__ Kb,
    const short* __restrict__ QR, const short* __restrict__ KR,
    const short* __restrict__ Vt, const f32x4* __restrict__ avg4,
    const int* __restrict__ ids, float* __restrict__ m_part,
    float* __restrict__ l_part, float* __restrict__ acc_part) {
  int h = blockIdx.y, sp = blockIdx.z;
  int w = threadIdx.x >> 6, lane = threadIdx.x & 63;
  int c = lane & 15, g = lane >> 4;
  int i0 = blockIdx.x * 64 + w * 16;
  int hk = h * 64;

  // [2 buf][64 rows][64 shorts]; 16B chunk at (row, ch) holds global chunk ch^(row&7)
  __shared__ short kb_lds[2][64 * 64];
  __shared__ short kr_lds[2][64 * 64];
  __shared__ short plds[4][16][72];

  // staging: wave w covers rows w*16..w*16+15 per subtile; lane l -> dest row
  // r0+ (l>>3), dest chunk l&7, source chunk (l&7)^(l>>3)  (r0 % 8 == 0)
  int srow = lane >> 3;
  int sxor = (lane & 7) ^ srow;
  int r0a = w * 16, r0b = w * 16 + 8;

  bf16x8 qA[2], qrA[2];
  {
    const short* qp = Qs + (size_t)(i0 + c) * D + hk + g * 8;
    const short* qrp = QR + (size_t)(i0 + c) * D + hk + g * 8;
    qA[0] = *(const bf16x8*)qp;   qA[1] = *(const bf16x8*)(qp + 32);
    qrA[0] = *(const bf16x8*)qrp; qrA[1] = *(const bf16x8*)(qrp + 32);
  }

  int idi[4];
  float mrun[4], lsum[4];
  f32x4 acc[4];
#pragma unroll
  for (int r = 0; r < 4; ++r) {
    idi[r] = ids[i0 + g * 4 + r];
    mrun[r] = -3.0e38f;
    lsum[r] = 0.f;
  }
#pragma unroll
  for (int n = 0; n < 4; ++n) acc[n] = (f32x4){0.f, 0.f, 0.f, 0.f};

  const f32x4* avrow = avg4 + (size_t)((i0 >> 2) + g) * L;
  int jbase = sp * JCH;
  const int NT = JCH / 64;

  // prologue: stage tile 0 + prefetch tile 0 avg/ids
  gll16(Kb + (size_t)(jbase + r0a + srow) * D + hk + sxor * 8, &kb_lds[0][r0a * 64]);
  gll16(Kb + (size_t)(jbase + r0b + srow) * D + hk + sxor * 8, &kb_lds[0][r0b * 64]);
  gll16(KR + (size_t)(jbase + r0a + srow) * D + hk + sxor * 8, &kr_lds[0][r0a * 64]);
  gll16(KR + (size_t)(jbase + r0b + srow) * D + hk + sxor * 8, &kr_lds[0][r0b * 64]);

  f32x4 avn[4];
  int idjn[4];
#pragma unroll
  for (int sub = 0; sub < 4; ++sub) {
    avn[sub] = avrow[jbase + sub * 16 + c];
    idjn[sub] = ids[jbase + sub * 16 + c];
  }
  __syncthreads();  // drains vmcnt -> tile 0 staged

  int cur = 0;
  for (int jt = 0; jt < NT; ++jt) {
    int jb = jbase + jt * 64;

    // issue next tile's staging (in flight during this tile's compute)
    if (jt + 1 < NT) {
      int jn = jb + 64;
      short* kd = &kb_lds[cur ^ 1][0];
      short* rd = &kr_lds[cur ^ 1][0];
      gll16(Kb + (size_t)(jn + r0a + srow) * D + hk + sxor * 8, kd + r0a * 64);
      gll16(Kb + (size_t)(jn + r0b + srow) * D + hk + sxor * 8, kd + r0b * 64);
      gll16(KR + (size_t)(jn + r0a + srow) * D + hk + sxor * 8, rd + r0a * 64);
      gll16(KR + (size_t)(jn + r0b + srow) * D + hk + sxor * 8, rd + r0b * 64);
    }

    // V loads early (consumed at PV, covered by QK+softmax)
    bf16x8 vf0[4], vf1[4];
#pragma unroll
    for (int n = 0; n < 4; ++n) {
      const short* vp = Vt + (size_t)(hk + n * 16 + c) * L + jb + g * 8;
      vf0[n] = *(const bf16x8*)vp;
      vf1[n] = *(const bf16x8*)(vp + 32);
    }

    // rotate avg/ids, prefetch next tile's
    f32x4 av[4];
    int idj[4];
#pragma unroll
    for (int sub = 0; sub < 4; ++sub) { av[sub] = avn[sub]; idj[sub] = idjn[sub]; }
    if (jt + 1 < NT) {
#pragma unroll
      for (int sub = 0; sub < 4; ++sub) {
        avn[sub] = avrow[jb + 64 + sub * 16 + c];
        idjn[sub] = ids[jb + 64 + sub * 16 + c];
      }
    }

    // QK^T from LDS (swizzled reads: chunk wanted ^ (row&7), row&7 == c&7)
    const short* kbb = &kb_lds[cur][c * 64];
    const short* krb = &kr_lds[cur][c * 64];
    int co0 = (g ^ (c & 7)) * 8;
    int co1 = ((4 + g) ^ (c & 7)) * 8;
    f32x4 raw[4], rpe[4];
#pragma unroll
    for (int sub = 0; sub < 4; ++sub) {
      bf16x8 k0 = *(const bf16x8*)(kbb + sub * 1024 + co0);
      bf16x8 k1 = *(const bf16x8*)(kbb + sub * 1024 + co1);
      bf16x8 kr0 = *(const bf16x8*)(krb + sub * 1024 + co0);
      bf16x8 kr1 = *(const bf16x8*)(krb + sub * 1024 + co1);
      f32x4 z = (f32x4){0.f, 0.f, 0.f, 0.f};
      raw[sub] = MFMA(qA[1], k1, MFMA(qA[0], k0, z));
      rpe[sub] = MFMA(qrA[1], kr1, MFMA(qrA[0], kr0, z));
    }

    float t[4][4];
#pragma unroll
    for (int sub = 0; sub < 4; ++sub)
#pragma unroll
      for (int r = 0; r < 4; ++r) {
        float sv = (idi[r] == idj[sub]) ? rpe[sub][r] : (raw[sub][r] + av[sub][r]);
        t[sub][r] = sv * LOG2E;
      }

    // defer-max: only reduce/rescale when tile max approaches the bound
    float tm[4];
#pragma unroll
    for (int r = 0; r < 4; ++r)
      tm[r] = fmaxf(fmaxf(t[0][r], t[1][r]), fmaxf(t[2][r], t[3][r]));
    bool ok = (tm[0] <= mrun[0] + 8.f) && (tm[1] <= mrun[1] + 8.f) &&
              (tm[2] <= mrun[2] + 8.f) && (tm[3] <= mrun[3] + 8.f);
    if (!__all(ok)) {
#pragma unroll
      for (int r = 0; r < 4; ++r) {
        float m2 = tm[r];
#pragma unroll
        for (int d = 1; d < 16; d <<= 1) m2 = fmaxf(m2, __shfl_xor(m2, d));
        float mn = fmaxf(mrun[r], m2);
        float so = exp2f(mrun[r] - mn);
        mrun[r] = mn;
        lsum[r] *= so;
#pragma unroll
        for (int n = 0; n < 4; ++n) acc[n][r] *= so;
      }
    }

    // p = exp2(t - m), pack to LDS (wave-private tile; same-wave DS ordering)
#pragma unroll
    for (int sub = 0; sub < 4; ++sub)
#pragma unroll
      for (int r = 0; r < 4; ++r) {
        float p = exp2f(t[sub][r] - mrun[r]);
        lsum[r] += p;
        plds[w][g * 4 + r][sub * 16 + c] = f2bf(p);
      }

    // PV: two K=32 chunks with preloaded V fragments
    {
      bf16x8 pa = *(const bf16x8*)(&plds[w][c][g * 8]);
#pragma unroll
      for (int n = 0; n < 4; ++n) acc[n] = MFMA(pa, vf0[n], acc[n]);
      bf16x8 pb = *(const bf16x8*)(&plds[w][c][32 + g * 8]);
#pragma unroll
      for (int n = 0; n < 4; ++n) acc[n] = MFMA(pb, vf1[n], acc[n]);
    }

    __syncthreads();  // drains vmcnt (next tile staged) + guards LDS buffer swap
    cur ^= 1;
  }

  // cross-lane reduce of lsum (m already lane-uniform within group)
#pragma unroll
  for (int r = 0; r < 4; ++r) {
#pragma unroll
    for (int d = 1; d < 16; d <<= 1) lsum[r] += __shfl_xor(lsum[r], d);
  }
  size_t sb = (size_t)(sp * NH + h) * L;
  if (c == 0) {
#pragma unroll
    for (int r = 0; r < 4; ++r) {
      m_part[sb + i0 + g * 4 + r] = mrun[r];
      l_part[sb + i0 + g * 4 + r] = lsum[r];
    }
  }
#pragma unroll
  for (int n = 0; n < 4; ++n)
#pragma unroll
    for (int r = 0; r < 4; ++r)
      acc_part[(sb + i0 + g * 4 + r) * HD + n * 16 + c] = acc[n][r];
}

// ---------------------------------------------------------------- merge partials
__global__ void merge_kernel(const float* __restrict__ m_part,
                             const float* __restrict__ l_part,
                             const float* __restrict__ acc_part,
                             float* __restrict__ mfin, float* __restrict__ lfin,
                             short* __restrict__ attn_bf) {
  int idx = blockIdx.x * 256 + threadIdx.x;  // NH*L*HD
  int d = idx & (HD - 1);
  int hi = idx >> 6;          // h*L + i
  int i = hi & (L - 1), h = hi >> 11;
  float m4 = -3.0e38f;
#pragma unroll
  for (int s = 0; s < SPLIT; ++s)
    m4 = fmaxf(m4, m_part[(size_t)(s * NH + h) * L + i]);
  float l = 0.f, o = 0.f;
#pragma unroll
  for (int s = 0; s < SPLIT; ++s) {
    size_t sb = (size_t)(s * NH + h) * L + i;
    float e = exp2f(m_part[sb] - m4);
    l += l_part[sb] * e;
    o += acc_part[sb * HD + d] * e;
  }
  attn_bf[(size_t)i * D + h * HD + d] = f2bf(o / l);
  if (d == 0) { mfin[h * L + i] = m4; lfin[h * L + i] = l; }
}

// ---------------------------------------------------------------- probs mean
// grid (L/64 j, L/64 i). 4 waves; 16 rows x 64 cols each. K/KR head-tiles staged
// in LDS (double-buffered, XOR-swizzled, head-ahead prefetch); Q pipelined in regs.
// NOTE: head loop intentionally NOT unrolled (VGPR pressure -> occupancy).
__global__ __launch_bounds__(256) void pavg_kernel(
    const short* __restrict__ Qs, const short* __restrict__ Kb,
    const short* __restrict__ QR, const short* __restrict__ KR,
    const f32x4* __restrict__ avg4, const int* __restrict__ ids,
    const float* __restrict__ m_ws, const float* __restrict__ l_ws,
    float* __restrict__ out1) {
  int j0 = blockIdx.x * 64;
  int iblk = blockIdx.y * 64;
  int w = threadIdx.x >> 6, lane = threadIdx.x & 63;
  int c = lane & 15, g = lane >> 4;
  int i0 = iblk + w * 16;

  __shared__ short kb_lds[2][64 * 64];
  __shared__ short kr_lds[2][64 * 64];
  __shared__ float mS[NH][64], lS[NH][64];

  // staging geometry (same as flash3): LDS[row][ch] = global[row][ch^(row&7)]
  int srow = lane >> 3;
  int sxor = (lane & 7) ^ srow;
  int r0a = w * 16, r0b = w * 16 + 8;

  for (int idx = threadIdx.x; idx < NH * 64; idx += 256) {
    int hh = idx >> 6, rr = idx & 63;
    mS[hh][rr] = m_ws[hh * L + iblk + rr];
    lS[hh][rr] = 1.0f / l_ws[hh * L + iblk + rr];
  }

  // stage head 0 K/KR tiles
  gll16(Kb + (size_t)(j0 + r0a + srow) * D + sxor * 8, &kb_lds[0][r0a * 64]);
  gll16(Kb + (size_t)(j0 + r0b + srow) * D + sxor * 8, &kb_lds[0][r0b * 64]);
  gll16(KR + (size_t)(j0 + r0a + srow) * D + sxor * 8, &kr_lds[0][r0a * 64]);
  gll16(KR + (size_t)(j0 + r0b + srow) * D + sxor * 8, &kr_lds[0][r0b * 64]);

  int idi[4], idj[4];
  f32x4 av[4];
  {
    const f32x4* avrow = avg4 + (size_t)((i0 >> 2) + g) * L;
#pragma unroll
    for (int sub = 0; sub < 4; ++sub) {
      av[sub] = avrow[j0 + sub * 16 + c];
      idj[sub] = ids[j0 + sub * 16 + c];
    }
#pragma unroll
    for (int r = 0; r < 4; ++r) idi[r] = ids[i0 + g * 4 + r];
  }

  f32x4 psum[4];
#pragma unroll
  for (int sub = 0; sub < 4; ++sub) psum[sub] = (f32x4){0.f, 0.f, 0.f, 0.f};

  const short* qbase = Qs + (size_t)(i0 + c) * D + g * 8;
  const short* qrbase = QR + (size_t)(i0 + c) * D + g * 8;

  // prefetch head 0 Q fragments
  bf16x8 nq0 = *(const bf16x8*)qbase, nq1 = *(const bf16x8*)(qbase + 32);
  bf16x8 nqr0 = *(const bf16x8*)qrbase, nqr1 = *(const bf16x8*)(qrbase + 32);

  __syncthreads();  // drains vmcnt -> head 0 staged; mS/lS ready

  int cur = 0;
#pragma unroll 1
  for (int hh = 0; hh < NH; ++hh) {
    // issue next head's K staging (in flight during this head's compute)
    if (hh + 1 < NH) {
      int hkn = (hh + 1) * 64;
      short* kd = &kb_lds[cur ^ 1][0];
      short* rd = &kr_lds[cur ^ 1][0];
      gll16(Kb + (size_t)(j0 + r0a + srow) * D + hkn + sxor * 8, kd + r0a * 64);
      gll16(Kb + (size_t)(j0 + r0b + srow) * D + hkn + sxor * 8, kd + r0b * 64);
      gll16(KR + (size_t)(j0 + r0a + srow) * D + hkn + sxor * 8, rd + r0a * 64);
      gll16(KR + (size_t)(j0 + r0b + srow) * D + hkn + sxor * 8, rd + r0b * 64);
    }

    // rotate Q, prefetch next head's Q
    bf16x8 q0 = nq0, q1 = nq1, qr0 = nqr0, qr1 = nqr1;
    if (hh + 1 < NH) {
      int hkn = (hh + 1) * 64;
      nq0 = *(const bf16x8*)(qbase + hkn);
      nq1 = *(const bf16x8*)(qbase + hkn + 32);
      nqr0 = *(const bf16x8*)(qrbase + hkn);
      nqr1 = *(const bf16x8*)(qrbase + hkn + 32);
    }

    // QK^T from LDS (swizzled reads)
    const short* kbb = &kb_lds[cur][c * 64];
    const short* krb = &kr_lds[cur][c * 64];
    int co0 = (g ^ (c & 7)) * 8;
    int co1 = ((4 + g) ^ (c & 7)) * 8;
    f32x4 raw[4], rpe[4];
#pragma unroll
    for (int sub = 0; sub < 4; ++sub) {
      bf16x8 k0 = *(const bf16x8*)(kbb + sub * 1024 + co0);
      bf16x8 k1 = *(const bf16x8*)(kbb + sub * 1024 + co1);
      bf16x8 kr0 = *(const bf16x8*)(krb + sub * 1024 + co0);
      bf16x8 kr1 = *(const bf16x8*)(krb + sub * 1024 + co1);
      f32x4 z = (f32x4){0.f, 0.f, 0.f, 0.f};
      raw[sub] = MFMA(q1, k1, MFMA(q0, k0, z));
      rpe[sub] = MFMA(qr1, kr1, MFMA(qr0, kr0, z));
    }

    f32x4 m4 = *(const f32x4*)(&mS[hh][w * 16 + g * 4]);
    f32x4 l4 = *(const f32x4*)(&lS[hh][w * 16 + g * 4]);
#pragma unroll
    for (int sub = 0; sub < 4; ++sub)
#pragma unroll
      for (int r = 0; r < 4; ++r) {
        float s = (idi[r] == idj[sub]) ? rpe[sub][r] : (raw[sub][r] + av[sub][r]);
        psum[sub][r] += exp2f(s * LOG2E - m4[r]) * l4[r];
      }

    __syncthreads();  // next head staged + guards LDS buffer swap
    cur ^= 1;
  }

#pragma unroll
  for (int sub = 0; sub < 4; ++sub)
#pragma unroll
    for (int r = 0; r < 4; ++r)
      out1[(size_t)(i0 + g * 4 + r) * L + j0 + sub * 16 + c] = psum[sub][r] * 0.0625f;
}

// ---------------------------------------------------------------- out proj
__global__ __launch_bounds__(256) void outproj_kernel(
    const short* __restrict__ A, const short* __restrict__ W,
    const float* __restrict__ bias, float* __restrict__ out) {
  int w = threadIdx.x >> 6, lane = threadIdx.x & 63;
  int c = lane & 15, g = lane >> 4;
  int wi0 = blockIdx.y * 128 + (w >> 1) * 64;
  int wj0 = blockIdx.x * 128 + (w & 1) * 64;

  f32x4 acc[4][4];
#pragma unroll
  for (int m = 0; m < 4; ++m)
#pragma unroll
    for (int n = 0; n < 4; ++n) acc[m][n] = (f32x4){0.f, 0.f, 0.f, 0.f};

  for (int k0 = 0; k0 < D; k0 += 32) {
    bf16x8 aF[4], bF[4];
#pragma unroll
    for (int m = 0; m < 4; ++m)
      aF[m] = *(const bf16x8*)(A + (size_t)(wi0 + m * 16 + c) * D + k0 + g * 8);
#pragma unroll
    for (int n = 0; n < 4; ++n)
      bF[n] = *(const bf16x8*)(W + (size_t)(wj0 + n * 16 + c) * D + k0 + g * 8);
#pragma unroll
    for (int m = 0; m < 4; ++m)
#pragma unroll
      for (int n = 0; n < 4; ++n) acc[m][n] = MFMA(aF[m], bF[n], acc[m][n]);
  }

#pragma unroll
  for (int m = 0; m < 4; ++m)
#pragma unroll
    for (int n = 0; n < 4; ++n)
#pragma unroll
      for (int r = 0; r < 4; ++r) {
        int i = wi0 + m * 16 + g * 4 + r;
        int col = wj0 + n * 16 + c;
        out[(size_t)i * D + col] = acc[m][n][r] + bias[col];
      }
}

// ---------------------------------------------------------------- launch
extern "C" void kernel_launch(void* const* d_in, const int* in_sizes, int n_in,
                              void* d_out, int out_size, void* d_ws, size_t ws_size,
                              hipStream_t stream) {
  const float* query = (const float*)d_in[0];
  const int* ids = (const int*)d_in[1];
  const float* wq = (const float*)d_in[2];
  const float* bq = (const float*)d_in[3];
  const float* wk = (const float*)d_in[4];
  const float* bk = (const float*)d_in[5];
  const float* wv = (const float*)d_in[6];
  const float* bv = (const float*)d_in[7];
  const float* wo = (const float*)d_in[8];
  const float* bo = (const float*)d_in[9];

  char* p = (char*)d_ws;
  auto carve = [&](size_t bytes) {
    char* r = p;
    p += (bytes + 255) & ~(size_t)255;
    return r;
  };
  short* Xbf = (short*)carve((size_t)L * D * 2);
  short* Wqb = (short*)carve((size_t)D * D * 2);
  short* Wkb = (short*)carve((size_t)D * D * 2);
  short* Wvb = (short*)carve((size_t)D * D * 2);
  short* Wob = (short*)carve((size_t)D * D * 2);
  short* Qs = (short*)carve((size_t)L * D * 2);
  short* QRb = (short*)carve((size_t)L * D * 2);
  short* Kbb = (short*)carve((size_t)L * D * 2);
  short* KRb = (short*)carve((size_t)L * D * 2);
  short* Vt = (short*)carve((size_t)L * D * 2);
  f32x4* avg4 = (f32x4*)carve((size_t)L * L * 4);
  float* m_ws = (float*)carve((size_t)NH * L * 4);
  float* l_ws = (float*)carve((size_t)NH * L * 4);
  short* attn_bf = (short*)carve((size_t)L * D * 2);
  float* costab = (float*)carve((size_t)L * 32 * 4);
  float* sintab = (float*)carve((size_t)L * 32 * 4);
  float* m_part = (float*)carve((size_t)SPLIT * NH * L * 4);
  float* l_part = (float*)carve((size_t)SPLIT * NH * L * 4);
  float* acc_part = (float*)carve((size_t)SPLIT * NH * L * HD * 4);

  float* out0 = (float*)d_out;                  // (L, 1, D)
  float* out1 = out0 + (size_t)L * D;           // (1, L, L)

  trig_kernel<<<(L * 32) / 256, 256, 0, stream>>>(costab, sintab);

  f2bf4_kernel<<<(L * D / 4 + 255) / 256, 256, 0, stream>>>(query, Xbf, L * D / 4);
  f2bf4_kernel<<<(D * D / 4 + 255) / 256, 256, 0, stream>>>(wq, Wqb, D * D / 4);
  f2bf4_kernel<<<(D * D / 4 + 255) / 256, 256, 0, stream>>>(wk, Wkb, D * D / 4);
  f2bf4_kernel<<<(D * D / 4 + 255) / 256, 256, 0, stream>>>(wv, Wvb, D * D / 4);
  f2bf4_kernel<<<(D * D / 4 + 255) / 256, 256, 0, stream>>>(wo, Wob, D * D / 4);

  dim3 gproj(D / 128, L / 128);
  proj_kernel<<<gproj, 256, 0, stream>>>(Xbf, Wqb, bq, costab, sintab, 0, Qs, QRb);
  proj_kernel<<<gproj, 256, 0, stream>>>(Xbf, Wkb, bk, costab, sintab, 1, Kbb, KRb);
  proj_kernel<<<gproj, 256, 0, stream>>>(Xbf, Wvb, bv, costab, sintab, 2, Vt, nullptr);

  avg_kernel<<<dim3(L / 128, L / 128), 256, 0, stream>>>(QRb, KRb, Qs, Kbb, avg4);

  flash3_kernel<<<dim3(L / 64, NH, SPLIT), 256, 0, stream>>>(
      Qs, Kbb, QRb, KRb, Vt, avg4, ids, m_part, l_part, acc_part);

  merge_kernel<<<(NH * L * HD) / 256, 256, 0, stream>>>(m_part, l_part, acc_part,
                                                        m_ws, l_ws, attn_bf);

  pavg_kernel<<<dim3(L / 64, L / 64), 256, 0, stream>>>(Qs, Kbb, QRb, KRb, avg4, ids,
                                                        m_ws, l_ws, out1);

  outproj_kernel<<<dim3(D / 128, L / 128), 256, 0, stream>>>(attn_bf, Wob, bo, out0);
}